// Round 7
// baseline (1383.010 us; speedup 1.0000x reference)
//
#include <hip/hip_runtime.h>
#include <hip/hip_bf16.h>

#define N_NODES 100000
#define N_EDGES 1600000
#define D 128
#define N_TILES (N_NODES / 16)   // 6250
#define NB 196                   // coarse buckets: 512 rows each (row>>9)
#define NF 1563                  // fine buckets: 64 rows each (row>>6), ceil(100000/64)
#define HIST_WGS 782             // ceil(N_EDGES/2048); each WG handles 2048 edges
#define CAP 16                   // LDS staging depth per coarse bucket

typedef __bf16 bf16x8 __attribute__((ext_vector_type(8)));
typedef float  f32x4  __attribute__((ext_vector_type(4)));
typedef int    i32x2  __attribute__((ext_vector_type(2)));

// ---- K2: fused coarse histogram (LDS-staged) + W transpose ----
__global__ __launch_bounds__(256) void hist_transpose_kernel(
        const int* __restrict__ rows,
        const float* __restrict__ W, __bf16* __restrict__ WT,
        int* __restrict__ coarseCounts) {
    int wg = blockIdx.x;
    if (wg >= HIST_WGS) {                 // 64 transpose WGs
        int t = (wg - HIST_WGS) * 256 + threadIdx.x;
        int k = t >> 7, n = t & 127;
        WT[n * D + k] = (__bf16)W[t];
        return;
    }
    __shared__ int lh[NB];
    if (threadIdx.x < NB) lh[threadIdx.x] = 0;
    __syncthreads();
    int base = wg * 2048;
    for (int it = 0; it < 8; ++it) {
        int e = base + it * 256 + threadIdx.x;
        if (e < N_EDGES) atomicAdd(&lh[rows[e] >> 9], 1);
    }
    __syncthreads();
    if (threadIdx.x < NB && lh[threadIdx.x])
        atomicAdd(&coarseCounts[threadIdx.x], lh[threadIdx.x]);
}

// ---- K3: exclusive scan over 196 coarse counts (single WG) ----
__global__ __launch_bounds__(256) void scan_kernel(const int* __restrict__ counts,
                                                   int* __restrict__ off,
                                                   int* __restrict__ cur) {
    __shared__ int sm[256];
    int t = threadIdx.x;
    int v = (t < NB) ? counts[t] : 0;
    sm[t] = v;
    __syncthreads();
    for (int d = 1; d < 256; d <<= 1) {
        int x = (t >= d) ? sm[t - d] : 0;
        __syncthreads();
        sm[t] += x;
        __syncthreads();
    }
    if (t < NB) { int ex = sm[t] - v; off[t] = ex; cur[t] = ex; }
    if (t == NB - 1) off[NB] = sm[t];
}

// ---- GEMM: h = bf16(x) @ bf16(W) (unchanged from R6, verified) ----
__global__ __launch_bounds__(256) void gemm_kernel(
        const float* __restrict__ x,
        const __bf16* __restrict__ WT,
        __bf16* __restrict__ h) {
    __shared__ __bf16 lsm[4][16][144];
    const int wave = threadIdx.x >> 6;
    const int lane = threadIdx.x & 63;
    const int tile = blockIdx.x * 4 + wave;
    if (tile >= N_TILES) return;
    const int m = lane & 15, quad = lane >> 4;
    const float* xp = x + (size_t)(tile * 16 + m) * D + quad * 8;

    f32x4 acc[8];
#pragma unroll
    for (int ct = 0; ct < 8; ++ct) acc[ct] = (f32x4)(0.0f);
#pragma unroll
    for (int kk = 0; kk < 4; ++kk) {
        f32x4 a0 = *(const f32x4*)(xp + kk * 32);
        f32x4 a1 = *(const f32x4*)(xp + kk * 32 + 4);
        bf16x8 a;
#pragma unroll
        for (int j = 0; j < 4; ++j) { a[j] = (__bf16)a0[j]; a[j + 4] = (__bf16)a1[j]; }
#pragma unroll
        for (int ct = 0; ct < 8; ++ct) {
            bf16x8 b = *(const bf16x8*)(WT + (size_t)(ct * 16 + m) * D + kk * 32 + quad * 8);
            acc[ct] = __builtin_amdgcn_mfma_f32_16x16x32_bf16(a, b, acc[ct], 0, 0, 0);
        }
    }
#pragma unroll
    for (int ct = 0; ct < 8; ++ct)
#pragma unroll
        for (int r = 0; r < 4; ++r)
            lsm[wave][quad * 4 + r][ct * 16 + m] = (__bf16)acc[ct][r];
#pragma unroll
    for (int i = 0; i < 4; ++i) {
        int rl = i * 4 + quad;
        bf16x8 vv = *(const bf16x8*)&lsm[wave][rl][m * 8];
        *(bf16x8*)(h + (size_t)(tile * 16 + rl) * D + m * 8) = vv;
    }
}

// ---- K4: staged coarse scatter. pack = ((row&511)<<17)|col, val as bits ----
__global__ __launch_bounds__(256) void scatterA_kernel(
        const int* __restrict__ rows, const int* __restrict__ cols,
        const float* __restrict__ vals,
        int* __restrict__ cur, i32x2* __restrict__ svcA) {
    __shared__ i32x2 buf[NB][CAP];   // 25 KB
    __shared__ int   cnt[NB];
    if (threadIdx.x < NB) cnt[threadIdx.x] = 0;
    __syncthreads();
    int base = blockIdx.x * 2048;
    for (int it = 0; it < 8; ++it) {
        int e = base + it * 256 + threadIdx.x;
        if (e < N_EDGES) {
            int r = rows[e];
            int b = r >> 9;
            i32x2 pk;
            pk[0] = ((r & 511) << 17) | cols[e];
            pk[1] = __float_as_int(vals[e]);
            int p = atomicAdd(&cnt[b], 1);
            if (p < CAP) buf[b][p] = pk;
            else {                         // ~1% overflow: direct claim+store
                int g = atomicAdd(&cur[b], 1);
                svcA[g] = pk;
            }
        }
    }
    __syncthreads();
    int t = threadIdx.x;
    if (t < NB) {
        int n = min(cnt[t], CAP);
        if (n > 0) {
            int g = atomicAdd(&cur[t], n);
            for (int i = 0; i < n; ++i) svcA[g + i] = buf[t][i];  // contiguous, one XCD
        }
    }
}

// ---- K5: fine partition within each coarse bucket (L2-resident window) ----
__global__ __launch_bounds__(1024) void scatterB_kernel(
        const int* __restrict__ off, const i32x2* __restrict__ svcA,
        i32x2* __restrict__ svcB, int* __restrict__ fineStart) {
    const int b    = blockIdx.x;
    const int base = off[b];
    const int n    = off[b + 1] - base;
    __shared__ int fcnt[8], floc[8], fcur[8];
    if (threadIdx.x < 8) fcnt[threadIdx.x] = 0;
    __syncthreads();

    // pass 1: per-lane predicated counts -> wave reduce -> LDS
    int c[8];
#pragma unroll
    for (int q = 0; q < 8; ++q) c[q] = 0;
    for (int i = threadIdx.x; i < n; i += 1024) {
        int s = svcA[base + i][0] >> 23;   // (row&511)>>6
#pragma unroll
        for (int q = 0; q < 8; ++q) c[q] += (s == q) ? 1 : 0;
    }
#pragma unroll
    for (int q = 0; q < 8; ++q) {
        int v = c[q];
        for (int o = 32; o; o >>= 1) v += __shfl_down(v, o, 64);
        if ((threadIdx.x & 63) == 0 && v) atomicAdd(&fcnt[q], v);
    }
    __syncthreads();
    if (threadIdx.x == 0) {
        int acc = 0;
        for (int q = 0; q < 8; ++q) { floc[q] = acc; fcur[q] = acc; acc += fcnt[q]; }
    }
    __syncthreads();
    if (threadIdx.x < 8)
        fineStart[b * 8 + threadIdx.x] = base + floc[threadIdx.x];
    // pass 2: scatter within L2-resident window (same-XCD writes merge)
    for (int i = threadIdx.x; i < n; i += 1024) {
        i32x2 e = svcA[base + i];
        int s = e[0] >> 23;
        int p = atomicAdd(&fcur[s], 1);
        svcB[base + p] = e;
    }
}

// ---- K7: per-64-row-bucket segmented sum in LDS + fused relu ----
__global__ __launch_bounds__(256) void segsum_kernel(
        const __bf16* __restrict__ h, const int* __restrict__ fineStart,
        const i32x2* __restrict__ svcB, float* __restrict__ out) {
    __shared__ float acc[64 * D];   // 32 KB
    const int fb   = blockIdx.x;
    const int w    = threadIdx.x >> 6;
    const int lane = threadIdx.x & 63;
    for (int i = threadIdx.x; i < 64 * D; i += 256) acc[i] = 0.0f;
    __syncthreads();

    const int s0 = fineStart[fb], e0 = fineStart[fb + 1];
    const int n  = e0 - s0;
    const int L  = (n + 3) >> 2;            // contiguous chunk per wave
    int ws = s0 + w * L;
    int we = min(ws + L, e0);

    int i = ws;
    for (; i + 7 < we; i += 8) {
        i32x2 E[8];
        unsigned u[8];
#pragma unroll
        for (int j = 0; j < 8; ++j) E[j] = svcB[i + j];
#pragma unroll
        for (int j = 0; j < 8; ++j)
            u[j] = *((const unsigned*)(h + (size_t)(E[j][0] & 0x1FFFF) * D) + lane);
#pragma unroll
        for (int j = 0; j < 8; ++j) {
            float v  = __int_as_float(E[j][1]);
            int   rl = (E[j][0] >> 17) & 63;
            atomicAdd(&acc[rl * D + 2 * lane],     v * __int_as_float(u[j] << 16));
            atomicAdd(&acc[rl * D + 2 * lane + 1], v * __int_as_float(u[j] & 0xffff0000u));
        }
    }
    for (; i < we; ++i) {
        i32x2 E = svcB[i];
        unsigned u = *((const unsigned*)(h + (size_t)(E[0] & 0x1FFFF) * D) + lane);
        float v  = __int_as_float(E[1]);
        int   rl = (E[0] >> 17) & 63;
        atomicAdd(&acc[rl * D + 2 * lane],     v * __int_as_float(u << 16));
        atomicAdd(&acc[rl * D + 2 * lane + 1], v * __int_as_float(u & 0xffff0000u));
    }
    __syncthreads();

    const int rowbase = fb * 64;
    for (int idx = threadIdx.x; idx < 64 * 32; idx += 256) {
        int r = idx >> 5, c4 = idx & 31;
        if (rowbase + r < N_NODES) {
            f32x4 o = *(f32x4*)&acc[r * D + c4 * 4];
            o[0] = fmaxf(o[0], 0.f); o[1] = fmaxf(o[1], 0.f);
            o[2] = fmaxf(o[2], 0.f); o[3] = fmaxf(o[3], 0.f);
            *(f32x4*)(out + (size_t)(rowbase + r) * D + c4 * 4) = o;
        }
    }
}

extern "C" void kernel_launch(void* const* d_in, const int* in_sizes, int n_in,
                              void* d_out, int out_size, void* d_ws, size_t ws_size,
                              hipStream_t stream) {
    const float* x    = (const float*)d_in[0];
    const float* w    = (const float*)d_in[1];
    const float* vals = (const float*)d_in[2];
    const int*   rows = (const int*)d_in[3];
    const int*   cols = (const int*)d_in[4];
    float*       out  = (float*)d_out;

    // ---- workspace (~51.25 MB; R3 proved >= 51.6 MB usable) ----
    char* p = (char*)d_ws;
    __bf16* h            = (__bf16*)p;  p += (size_t)N_NODES * D * 2;   // 25.6 MB
    __bf16* WT           = (__bf16*)p;  p += (size_t)D * D * 2;         // 32 KB
    int*    coarseCounts = (int*)p;     p += 1024;
    int*    coarseOff    = (int*)p;     p += 1024;                      // NB+1 ints
    int*    coarseCur    = (int*)p;     p += 1024;
    int*    fineStart    = (int*)p;     p += 6400;                      // NB*8 ints
    i32x2*  svcA         = (i32x2*)p;   p += (size_t)N_EDGES * 8;       // 12.8 MB
    i32x2*  svcB         = (i32x2*)p;   p += (size_t)N_EDGES * 8;       // 12.8 MB

    (void)hipMemsetAsync(coarseCounts, 0, NB * sizeof(int), stream);

    hist_transpose_kernel<<<HIST_WGS + 64, 256, 0, stream>>>(rows, w, WT, coarseCounts);
    scan_kernel<<<1, 256, 0, stream>>>(coarseCounts, coarseOff, coarseCur);
    gemm_kernel<<<(N_TILES + 3) / 4, 256, 0, stream>>>(x, WT, h);
    scatterA_kernel<<<HIST_WGS, 256, 0, stream>>>(rows, cols, vals, coarseCur, svcA);
    scatterB_kernel<<<NB, 1024, 0, stream>>>(coarseOff, svcA, svcB, fineStart);
    segsum_kernel<<<NF, 256, 0, stream>>>(h, fineStart, svcB, out);
}

// Round 8
// 292.214 us; speedup vs baseline: 4.7329x; 4.7329x over previous
//
#include <hip/hip_runtime.h>
#include <hip/hip_bf16.h>

#define N_NODES 100000
#define N_EDGES 1600000
#define D 128
#define N_TILES (N_NODES / 16)   // 6250
#define NB 196                   // coarse buckets: 512 rows each (row>>9)
#define HIST_WGS 782             // ceil(N_EDGES/2048); each WG handles 2048 edges
#define CAP 16                   // LDS staging depth per coarse bucket

typedef __bf16 bf16x8 __attribute__((ext_vector_type(8)));
typedef float  f32x4  __attribute__((ext_vector_type(4)));
typedef float  f32x2  __attribute__((ext_vector_type(2)));
typedef int    i32x2  __attribute__((ext_vector_type(2)));

// ---- K1: fused coarse histogram (LDS-staged) + W transpose ----
__global__ __launch_bounds__(256) void hist_transpose_kernel(
        const int* __restrict__ rows,
        const float* __restrict__ W, __bf16* __restrict__ WT,
        int* __restrict__ coarseCounts) {
    int wg = blockIdx.x;
    if (wg >= HIST_WGS) {                 // 64 transpose WGs
        int t = (wg - HIST_WGS) * 256 + threadIdx.x;
        int k = t >> 7, n = t & 127;
        WT[n * D + k] = (__bf16)W[t];
        return;
    }
    __shared__ int lh[NB];
    if (threadIdx.x < NB) lh[threadIdx.x] = 0;
    __syncthreads();
    int base = wg * 2048;
    for (int it = 0; it < 8; ++it) {
        int e = base + it * 256 + threadIdx.x;
        if (e < N_EDGES) atomicAdd(&lh[rows[e] >> 9], 1);
    }
    __syncthreads();
    if (threadIdx.x < NB && lh[threadIdx.x])
        atomicAdd(&coarseCounts[threadIdx.x], lh[threadIdx.x]);
}

// ---- K2: exclusive scan over NB coarse counts (single WG) ----
__global__ __launch_bounds__(256) void scan_kernel(const int* __restrict__ counts,
                                                   int* __restrict__ off,
                                                   int* __restrict__ cur) {
    __shared__ int sm[256];
    int t = threadIdx.x;
    int v = (t < NB) ? counts[t] : 0;
    sm[t] = v;
    __syncthreads();
    for (int d = 1; d < 256; d <<= 1) {
        int x = (t >= d) ? sm[t - d] : 0;
        __syncthreads();
        sm[t] += x;
        __syncthreads();
    }
    if (t < NB) { int ex = sm[t] - v; off[t] = ex; cur[t] = ex; }
    if (t == NB - 1) off[NB] = sm[t];
}

// ---- GEMM: h = bf16(x) @ bf16(W) (verified since R6) ----
__global__ __launch_bounds__(256) void gemm_kernel(
        const float* __restrict__ x,
        const __bf16* __restrict__ WT,
        __bf16* __restrict__ h) {
    __shared__ __bf16 lsm[4][16][144];
    const int wave = threadIdx.x >> 6;
    const int lane = threadIdx.x & 63;
    const int tile = blockIdx.x * 4 + wave;
    if (tile >= N_TILES) return;
    const int m = lane & 15, quad = lane >> 4;
    const float* xp = x + (size_t)(tile * 16 + m) * D + quad * 8;

    f32x4 acc[8];
#pragma unroll
    for (int ct = 0; ct < 8; ++ct) acc[ct] = (f32x4)(0.0f);
#pragma unroll
    for (int kk = 0; kk < 4; ++kk) {
        f32x4 a0 = *(const f32x4*)(xp + kk * 32);
        f32x4 a1 = *(const f32x4*)(xp + kk * 32 + 4);
        bf16x8 a;
#pragma unroll
        for (int j = 0; j < 4; ++j) { a[j] = (__bf16)a0[j]; a[j + 4] = (__bf16)a1[j]; }
#pragma unroll
        for (int ct = 0; ct < 8; ++ct) {
            bf16x8 b = *(const bf16x8*)(WT + (size_t)(ct * 16 + m) * D + kk * 32 + quad * 8);
            acc[ct] = __builtin_amdgcn_mfma_f32_16x16x32_bf16(a, b, acc[ct], 0, 0, 0);
        }
    }
#pragma unroll
    for (int ct = 0; ct < 8; ++ct)
#pragma unroll
        for (int r = 0; r < 4; ++r)
            lsm[wave][quad * 4 + r][ct * 16 + m] = (__bf16)acc[ct][r];
#pragma unroll
    for (int i = 0; i < 4; ++i) {
        int rl = i * 4 + quad;
        bf16x8 vv = *(const bf16x8*)&lsm[wave][rl][m * 8];
        *(bf16x8*)(h + (size_t)(tile * 16 + rl) * D + m * 8) = vv;
    }
}

// ---- K3: staged coarse scatter. pack = ((row&511)<<17)|col, val as bits ----
__global__ __launch_bounds__(256) void scatterA_kernel(
        const int* __restrict__ rows, const int* __restrict__ cols,
        const float* __restrict__ vals,
        int* __restrict__ cur, i32x2* __restrict__ svcA) {
    __shared__ i32x2 buf[NB][CAP];   // 25 KB
    __shared__ int   cnt[NB];
    if (threadIdx.x < NB) cnt[threadIdx.x] = 0;
    __syncthreads();
    int base = blockIdx.x * 2048;
    for (int it = 0; it < 8; ++it) {
        int e = base + it * 256 + threadIdx.x;
        if (e < N_EDGES) {
            int r = rows[e];
            int b = r >> 9;
            i32x2 pk;
            pk[0] = ((r & 511) << 17) | cols[e];
            pk[1] = __float_as_int(vals[e]);
            int p = atomicAdd(&cnt[b], 1);
            if (p < CAP) buf[b][p] = pk;
            else {                         // rare overflow: direct claim+store
                int g = atomicAdd(&cur[b], 1);
                svcA[g] = pk;
            }
        }
    }
    __syncthreads();
    int t = threadIdx.x;
    if (t < NB) {
        int n = min(cnt[t], CAP);
        if (n > 0) {
            int g = atomicAdd(&cur[t], n);
            for (int i = 0; i < n; ++i) svcA[g + i] = buf[t][i];  // contiguous run
        }
    }
}

// ---- K4: exact per-row counting sort within each coarse bucket ----
// svcB becomes globally row-sorted; writes per-row global offsets.
__global__ __launch_bounds__(1024) void scatterB_kernel(
        const int* __restrict__ off, const i32x2* __restrict__ svcA,
        i32x2* __restrict__ svcB, int* __restrict__ offsets) {
    const int b    = blockIdx.x;
    const int base = off[b];
    const int n    = off[b + 1] - base;
    const int t    = threadIdx.x;
    __shared__ int hist[512];
    __shared__ int sm[512];
    __shared__ int cur[512];
    if (t < 512) hist[t] = 0;
    __syncthreads();
    for (int i = t; i < n; i += 1024)
        atomicAdd(&hist[svcA[base + i][0] >> 17], 1);
    __syncthreads();
    if (t < 512) sm[t] = hist[t];
    __syncthreads();
    for (int d = 1; d < 512; d <<= 1) {             // inclusive Hillis-Steele
        int v = (t < 512 && t >= d) ? sm[t - d] : 0;
        __syncthreads();
        if (t < 512) sm[t] += v;
        __syncthreads();
    }
    if (t < 512) {
        int excl = sm[t] - hist[t];
        cur[t] = excl;
        offsets[b * 512 + t] = base + excl;         // global per-row start
    }
    __syncthreads();
    for (int i = t; i < n; i += 1024) {             // L2-resident 65KB window
        i32x2 e = svcA[base + i];
        int p = atomicAdd(&cur[e[0] >> 17], 1);
        svcB[base + p] = e;
    }
}

// ---- K5: segmented sum + relu, register accumulators, 4-way MLP ----
// one wave per row; lane covers 2 features (one 4B bf16x2 gather per edge)
__global__ __launch_bounds__(256) void segsum_kernel(
        const __bf16* __restrict__ h, const int* __restrict__ offsets,
        const i32x2* __restrict__ svcB, float* __restrict__ out) {
    const int r    = blockIdx.x * 4 + (threadIdx.x >> 6);   // grid covers N_NODES
    const int lane = threadIdx.x & 63;

    const int start = offsets[r];
    const int end   = offsets[r + 1];   // svcB globally row-sorted

    float a0 = 0.f, b0 = 0.f, a1 = 0.f, b1 = 0.f;
    float a2 = 0.f, b2 = 0.f, a3 = 0.f, b3 = 0.f;

    int i = start;
    for (; i + 3 < end; i += 4) {
        i32x2 e0 = svcB[i], e1 = svcB[i + 1], e2 = svcB[i + 2], e3 = svcB[i + 3];
        unsigned u0 = *((const unsigned*)(h + (size_t)(e0[0] & 0x1FFFF) * D) + lane);
        unsigned u1 = *((const unsigned*)(h + (size_t)(e1[0] & 0x1FFFF) * D) + lane);
        unsigned u2 = *((const unsigned*)(h + (size_t)(e2[0] & 0x1FFFF) * D) + lane);
        unsigned u3 = *((const unsigned*)(h + (size_t)(e3[0] & 0x1FFFF) * D) + lane);
        float v0 = __int_as_float(e0[1]), v1 = __int_as_float(e1[1]);
        float v2 = __int_as_float(e2[1]), v3 = __int_as_float(e3[1]);
        a0 += v0 * __int_as_float(u0 << 16);  b0 += v0 * __int_as_float(u0 & 0xffff0000u);
        a1 += v1 * __int_as_float(u1 << 16);  b1 += v1 * __int_as_float(u1 & 0xffff0000u);
        a2 += v2 * __int_as_float(u2 << 16);  b2 += v2 * __int_as_float(u2 & 0xffff0000u);
        a3 += v3 * __int_as_float(u3 << 16);  b3 += v3 * __int_as_float(u3 & 0xffff0000u);
    }
    for (; i < end; ++i) {
        i32x2 e0 = svcB[i];
        unsigned u0 = *((const unsigned*)(h + (size_t)(e0[0] & 0x1FFFF) * D) + lane);
        float v0 = __int_as_float(e0[1]);
        a0 += v0 * __int_as_float(u0 << 16);  b0 += v0 * __int_as_float(u0 & 0xffff0000u);
    }

    f32x2 o;
    o[0] = fmaxf((a0 + a1) + (a2 + a3), 0.0f);
    o[1] = fmaxf((b0 + b1) + (b2 + b3), 0.0f);
    __builtin_nontemporal_store(o, (f32x2*)(out + (size_t)r * D + lane * 2));
}

extern "C" void kernel_launch(void* const* d_in, const int* in_sizes, int n_in,
                              void* d_out, int out_size, void* d_ws, size_t ws_size,
                              hipStream_t stream) {
    const float* x    = (const float*)d_in[0];
    const float* w    = (const float*)d_in[1];
    const float* vals = (const float*)d_in[2];
    const int*   rows = (const int*)d_in[3];
    const int*   cols = (const int*)d_in[4];
    float*       out  = (float*)d_out;

    // ---- workspace (~38.9 MB) ----
    char* p = (char*)d_ws;
    __bf16* h            = (__bf16*)p;  p += (size_t)N_NODES * D * 2;   // 25.6 MB
    __bf16* WT           = (__bf16*)p;  p += (size_t)D * D * 2;         // 32 KB
    int*    coarseCounts = (int*)p;     p += 1024;
    int*    coarseOff    = (int*)p;     p += 1024;                      // NB+1 ints
    int*    coarseCur    = (int*)p;     p += 1024;
    int*    offsets      = (int*)p;     p += (size_t)100608 * 4;        // NB*512+1 used
    i32x2*  svcB         = (i32x2*)p;   p += (size_t)N_EDGES * 8;       // 12.8 MB

    // svcA lives in d_out (dead before segsum writes output)
    i32x2*  svcA = (i32x2*)d_out;

    (void)hipMemsetAsync(coarseCounts, 0, NB * sizeof(int), stream);

    hist_transpose_kernel<<<HIST_WGS + 64, 256, 0, stream>>>(rows, w, WT, coarseCounts);
    scan_kernel<<<1, 256, 0, stream>>>(coarseCounts, coarseOff, coarseCur);
    gemm_kernel<<<(N_TILES + 3) / 4, 256, 0, stream>>>(x, WT, h);
    scatterA_kernel<<<HIST_WGS, 256, 0, stream>>>(rows, cols, vals, coarseCur, svcA);
    scatterB_kernel<<<NB, 1024, 0, stream>>>(coarseOff, svcA, svcB, offsets);
    segsum_kernel<<<N_NODES / 4, 256, 0, stream>>>(h, offsets, svcB, out);
}